// Round 1
// baseline (791.380 us; speedup 1.0000x reference)
//
#include <hip/hip_runtime.h>
#include <hip/hip_bf16.h>

#define TILE 64
#define BKK 16
#define NH 12
#define HD 64
#define MAXB 8  // supports up to 512 visible keys per row (actual: 260)

// ---------------- f32 tiled GEMM with bias: C[M,N] = A[M,K] @ B[K,N] + bias[N]
__global__ __launch_bounds__(256) void gemm_bias_f32(
    const float* __restrict__ A, const float* __restrict__ B,
    const float* __restrict__ bias, float* __restrict__ C,
    int M, int N, int K)
{
    __shared__ float As[BKK][TILE + 4];  // As[k][m], +4 pad keeps 16B align, breaks bank stride
    __shared__ float Bs[BKK][TILE];      // Bs[k][n]

    const int tid  = threadIdx.x;
    const int row0 = blockIdx.y * TILE;
    const int col0 = blockIdx.x * TILE;

    const int tr = ((tid >> 4) & 15) << 2;  // 0,4,8,12  (micro-tile row base)
    const int tc = (tid & 15) << 2;         // 0..60     (micro-tile col base)

    const int ar  = tid >> 2;   // 0..63  A-tile row
    const int ac4 = tid & 3;    // 0..3   A-tile k-group (float4)
    const int br  = tid >> 4;   // 0..15  B-tile k row
    const int bc4 = tid & 15;   // 0..15  B-tile n-group (float4)

    float acc[4][4] = {};

    for (int k0 = 0; k0 < K; k0 += BKK) {
        float4 av = *(const float4*)(&A[(size_t)(row0 + ar) * K + k0 + (ac4 << 2)]);
        float4 bv = *(const float4*)(&B[(size_t)(k0 + br) * N + col0 + (bc4 << 2)]);
        __syncthreads();  // previous iteration's reads done before overwrite
        As[(ac4 << 2) + 0][ar] = av.x;
        As[(ac4 << 2) + 1][ar] = av.y;
        As[(ac4 << 2) + 2][ar] = av.z;
        As[(ac4 << 2) + 3][ar] = av.w;
        *(float4*)(&Bs[br][bc4 << 2]) = bv;
        __syncthreads();
        #pragma unroll
        for (int kk = 0; kk < BKK; ++kk) {
            float4 af = *(const float4*)(&As[kk][tr]);
            float4 bf = *(const float4*)(&Bs[kk][tc]);
            float a4[4] = {af.x, af.y, af.z, af.w};
            float b4[4] = {bf.x, bf.y, bf.z, bf.w};
            #pragma unroll
            for (int ii = 0; ii < 4; ++ii)
                #pragma unroll
                for (int jj = 0; jj < 4; ++jj)
                    acc[ii][jj] += a4[ii] * b4[jj];
        }
    }

    float4 bv4 = *(const float4*)(&bias[col0 + tc]);
    float bb[4] = {bv4.x, bv4.y, bv4.z, bv4.w};
    #pragma unroll
    for (int ii = 0; ii < 4; ++ii) {
        float4 o;
        o.x = acc[ii][0] + bb[0];
        o.y = acc[ii][1] + bb[1];
        o.z = acc[ii][2] + bb[2];
        o.w = acc[ii][3] + bb[3];
        *(float4*)(&C[(size_t)(row0 + tr + ii) * N + col0 + tc]) = o;
    }
}

// ---------------- sink+window masked attention
// qkv layout: [S][3*D] with q at col h*64, k at D + h*64, v at 2D + h*64
// ctx layout: [S][D] with head h at cols h*64..h*64+63
// One wave (64 lanes) per (head, query row); 4 waves per block (4 consecutive rows).
__global__ __launch_bounds__(256) void attn_sink_window(
    const float* __restrict__ qkv, float* __restrict__ ctx,
    const int* __restrict__ pnsink, const int* __restrict__ pwin, int S)
{
    const int lane = threadIdx.x;            // 0..63
    const int w    = threadIdx.y;            // 0..3
    const int h    = blockIdx.y;             // 0..11
    const int i    = blockIdx.x * 4 + w;     // query row
    const int D    = NH * HD;                // 768
    const int D3   = 3 * D;                  // 2304

    const int nsink_in = *pnsink;
    const int wsize    = *pwin;

    __shared__ float qs[4][HD];
    __shared__ float ps[4][MAXB * 64];

    // load q row, pre-scaled by 1/sqrt(hd)
    qs[w][lane] = qkv[(size_t)i * D3 + h * HD + lane] * 0.125f;
    __syncthreads();

    // visible keys: sinks [0, nsink_eff) plus window [wlo, i]
    const int nsink_eff = min(nsink_in, i + 1);
    const int wstart    = max(i - wsize + 1, 0);
    const int wlo       = max(wstart, nsink_in);
    const int wcnt      = max(0, i - wlo + 1);
    const int n         = nsink_eff + wcnt;   // total visible (<= MAXB*64)

    // pass 1: scores, lane-per-key
    float sc[MAXB];
    float vmax = -INFINITY;
    #pragma unroll
    for (int b = 0; b < MAXB; ++b) {
        const int t = (b << 6) + lane;
        float s = -INFINITY;
        if (t < n) {
            const int j = (t < nsink_eff) ? t : wlo + (t - nsink_eff);
            const float* kr = &qkv[(size_t)j * D3 + D + h * HD];
            float dot = 0.f;
            #pragma unroll
            for (int d4 = 0; d4 < HD / 4; ++d4) {
                float4 kv = *(const float4*)(kr + (d4 << 2));
                dot += qs[w][(d4 << 2) + 0] * kv.x + qs[w][(d4 << 2) + 1] * kv.y
                     + qs[w][(d4 << 2) + 2] * kv.z + qs[w][(d4 << 2) + 3] * kv.w;
            }
            s = dot;
        }
        sc[b] = s;
        vmax = fmaxf(vmax, s);
    }
    #pragma unroll
    for (int off = 1; off < 64; off <<= 1)
        vmax = fmaxf(vmax, __shfl_xor(vmax, off));

    float lsum = 0.f;
    #pragma unroll
    for (int b = 0; b < MAXB; ++b) {
        const int t = (b << 6) + lane;
        const float p = (t < n) ? __expf(sc[b] - vmax) : 0.f;
        sc[b] = p;
        lsum += p;
    }
    #pragma unroll
    for (int off = 1; off < 64; off <<= 1)
        lsum += __shfl_xor(lsum, off);
    const float inv = 1.f / lsum;

    #pragma unroll
    for (int b = 0; b < MAXB; ++b) {
        const int t = (b << 6) + lane;
        if (t < n) ps[w][t] = sc[b] * inv;
    }
    __syncthreads();

    // pass 2: ctx[d = lane], coalesced V reads
    float c = 0.f;
    for (int t = 0; t < n; ++t) {
        const int j = (t < nsink_eff) ? t : wlo + (t - nsink_eff);
        c += ps[w][t] * qkv[(size_t)j * D3 + 2 * D + h * HD + lane];
    }
    ctx[(size_t)i * D + h * HD + lane] = c;
}

extern "C" void kernel_launch(void* const* d_in, const int* in_sizes, int n_in,
                              void* d_out, int out_size, void* d_ws, size_t ws_size,
                              hipStream_t stream) {
    const float* x      = (const float*)d_in[0];
    const float* w_attn = (const float*)d_in[1];
    const float* b_attn = (const float*)d_in[2];
    const float* w_proj = (const float*)d_in[3];
    const float* b_proj = (const float*)d_in[4];
    const int*   pnsink = (const int*)d_in[5];
    const int*   pwin   = (const int*)d_in[6];
    float* out = (float*)d_out;

    const int D  = 768;
    const int S  = in_sizes[0] / D;   // 4096
    const int N1 = 3 * D;             // 2304

    float* qkv_ws = (float*)d_ws;
    float* ctx_ws = qkv_ws + (size_t)S * N1;

    // GEMM1: qkv = x @ w_attn + b_attn   [S, 3D]
    {
        dim3 grid(N1 / TILE, S / TILE);
        gemm_bias_f32<<<grid, 256, 0, stream>>>(x, w_attn, b_attn, qkv_ws, S, N1, D);
    }
    // attention -> ctx [S, D]
    {
        dim3 grid(S / 4, NH);
        dim3 block(64, 4);
        attn_sink_window<<<grid, block, 0, stream>>>(qkv_ws, ctx_ws, pnsink, pwin, S);
    }
    // GEMM2: out = ctx @ w_proj + b_proj  [S, D]
    {
        dim3 grid(D / TILE, S / TILE);
        gemm_bias_f32<<<grid, 256, 0, stream>>>(ctx_ws, w_proj, b_proj, out, S, D, D);
    }
}

// Round 2
// 102.528 us; speedup vs baseline: 7.7187x; 7.7187x over previous
//
#include <hip/hip_runtime.h>
#include <hip/hip_bf16.h>
#include <stdint.h>

typedef short bf16x8 __attribute__((ext_vector_type(8)));
typedef unsigned short u16x8 __attribute__((ext_vector_type(8)));
typedef float f32x4 __attribute__((ext_vector_type(4)));

__device__ inline unsigned short f2bf(float f) {
    union { float f; uint32_t u; } v; v.f = f;
    uint32_t lsb = (v.u >> 16) & 1u;
    v.u += 0x7fffu + lsb;                // round-to-nearest-even
    return (unsigned short)(v.u >> 16);
}

// ---------------- elementwise f32 -> bf16 (8 per thread)
__global__ __launch_bounds__(256) void cast_f32_bf16(const float* __restrict__ in,
                                                     unsigned short* __restrict__ out, int n8) {
    int i = blockIdx.x * 256 + threadIdx.x;
    if (i >= n8) return;
    const float4* p = (const float4*)in + (size_t)i * 2;
    float4 a = p[0], b = p[1];
    u16x8 o;
    o[0] = f2bf(a.x); o[1] = f2bf(a.y); o[2] = f2bf(a.z); o[3] = f2bf(a.w);
    o[4] = f2bf(b.x); o[5] = f2bf(b.y); o[6] = f2bf(b.z); o[7] = f2bf(b.w);
    *((u16x8*)out + i) = o;
}

// ---------------- [R][C] f32 -> [C][R] bf16 transpose (64x64 tiles)
__global__ __launch_bounds__(256) void transpose_cast(const float* __restrict__ in,
                                                      unsigned short* __restrict__ out,
                                                      int R, int C) {
    __shared__ float tile[64][65];
    const int t = threadIdx.x;
    const int r0 = blockIdx.y * 64, c0 = blockIdx.x * 64;
    {
        int r = t >> 2, cs = t & 3;
        #pragma unroll
        for (int i = 0; i < 4; ++i) {
            int c = (cs * 4 + i) * 4;
            float4 v = *(const float4*)(in + (size_t)(r0 + r) * C + c0 + c);
            tile[r][c] = v.x; tile[r][c + 1] = v.y; tile[r][c + 2] = v.z; tile[r][c + 3] = v.w;
        }
    }
    __syncthreads();
    {
        int c = t >> 2, rs = t & 3;
        #pragma unroll
        for (int i = 0; i < 2; ++i) {
            u16x8 o;
            #pragma unroll
            for (int e = 0; e < 8; ++e) o[e] = f2bf(tile[rs * 16 + i * 8 + e][c]);
            *(u16x8*)(out + (size_t)(c0 + c) * R + r0 + rs * 16 + i * 8) = o;
        }
    }
}

// ---------------- bf16 MFMA GEMM: C[M,N] = A[M,K] @ BT[N,K]^T + bias
// 128x128 tile, BK=64, 4 waves (each 64x64 = 4x4 fragments of 16x16x32)
template <int OUT_BF16>
__global__ __launch_bounds__(256) void gemm_bf16(const unsigned short* __restrict__ A,
                                                 const unsigned short* __restrict__ BT,
                                                 const float* __restrict__ bias,
                                                 void* __restrict__ Cout,
                                                 int M, int N, int K) {
    __shared__ unsigned short As[128 * 64];
    __shared__ unsigned short Bs[128 * 64];
    const int tid = threadIdx.x;
    const int lane = tid & 63;
    const int wid = tid >> 6;
    const int wr = wid >> 1, wc = wid & 1;
    const int row0 = blockIdx.y * 128, col0 = blockIdx.x * 128;

    const int sr = tid >> 3;   // staging row base 0..31
    const int seg = tid & 7;   // 16B segment within 128B row

    f32x4 acc[4][4] = {};

    for (int k0 = 0; k0 < K; k0 += 64) {
        __syncthreads();
        #pragma unroll
        for (int i = 0; i < 4; ++i) {
            int r = sr + 32 * i;
            u16x8 av = *(const u16x8*)(A + (size_t)(row0 + r) * K + k0 + seg * 8);
            u16x8 bv = *(const u16x8*)(BT + (size_t)(col0 + r) * K + k0 + seg * 8);
            *(u16x8*)(As + r * 64 + seg * 8) = av;
            *(u16x8*)(Bs + r * 64 + seg * 8) = bv;
        }
        __syncthreads();
        bf16x8 af[4][2], bfr[4][2];
        #pragma unroll
        for (int m = 0; m < 4; ++m)
            #pragma unroll
            for (int ks = 0; ks < 2; ++ks) {
                af[m][ks]  = *(const bf16x8*)(As + (wr * 64 + m * 16 + (lane & 15)) * 64 + ks * 32 + (lane >> 4) * 8);
                bfr[m][ks] = *(const bf16x8*)(Bs + (wc * 64 + m * 16 + (lane & 15)) * 64 + ks * 32 + (lane >> 4) * 8);
            }
        #pragma unroll
        for (int m = 0; m < 4; ++m)
            #pragma unroll
            for (int n = 0; n < 4; ++n)
                #pragma unroll
                for (int ks = 0; ks < 2; ++ks)
                    acc[m][n] = __builtin_amdgcn_mfma_f32_16x16x32_bf16(af[m][ks], bfr[n][ks], acc[m][n], 0, 0, 0);
    }

    #pragma unroll
    for (int m = 0; m < 4; ++m) {
        int row = row0 + wr * 64 + m * 16 + (lane >> 4) * 4;
        #pragma unroll
        for (int n = 0; n < 4; ++n) {
            int col = col0 + wc * 64 + n * 16 + (lane & 15);
            float bb = bias[col];
            #pragma unroll
            for (int r = 0; r < 4; ++r) {
                float v = acc[m][n][r] + bb;
                if (OUT_BF16)
                    ((unsigned short*)Cout)[(size_t)(row + r) * N + col] = f2bf(v);
                else
                    ((float*)Cout)[(size_t)(row + r) * N + col] = v;
            }
        }
    }
}

// ---------------- flash-style sink+window attention, bf16 MFMA
// block: 64 queries x 1 head, 4 waves x 16 queries. Key tiles of 64.
__global__ __launch_bounds__(256) void attn_mfma(const unsigned short* __restrict__ qkv,
                                                 unsigned short* __restrict__ ctx,
                                                 const int* __restrict__ pnsink,
                                                 const int* __restrict__ pwin) {
    __shared__ unsigned short Qs[64 * 72];
    __shared__ unsigned short Ks[64 * 72];
    __shared__ unsigned short Vt[64 * 72];
    __shared__ unsigned short Ps[64 * 72];
    const int tid = threadIdx.x, lane = tid & 63, w = tid >> 6;
    const int h = blockIdx.y;
    const int i0 = blockIdx.x * 64;
    const int nsink = *pnsink, wsize = *pwin;
    const int D3 = 2304;

    // stage Q block [64 rows][64 d] (pad-72 rows)
    {
        int q = tid >> 2, s1 = tid & 3;
        const unsigned short* src = qkv + (size_t)(i0 + q) * D3 + h * 64;
        u16x8 v0 = *(const u16x8*)(src + s1 * 8);
        u16x8 v1 = *(const u16x8*)(src + (s1 + 4) * 8);
        *(u16x8*)(Qs + q * 72 + s1 * 8) = v0;
        *(u16x8*)(Qs + q * 72 + (s1 + 4) * 8) = v1;
    }

    float mrow[4], lrow[4];
    f32x4 ctxacc[4];
    #pragma unroll
    for (int r = 0; r < 4; ++r) { mrow[r] = -1e30f; lrow[r] = 0.f; ctxacc[r] = (f32x4){0, 0, 0, 0}; }

    int wlo = i0 - wsize + 1; if (wlo < 0) wlo = 0;
    const int t_lo = (wlo >> 6) << 6;
    const int iq = i0 + 16 * w + ((lane >> 4) << 2);   // +r gives this lane's query rows
    const int ntiles = ((i0 - t_lo) >> 6) + 1 + (t_lo > 0 ? 1 : 0);

    for (int tt = 0; tt < ntiles; ++tt) {
        int kb;
        if (t_lo > 0) kb = (tt == 0) ? 0 : t_lo + ((tt - 1) << 6);
        else          kb = tt << 6;

        __syncthreads();
        // stage K rows [64][64] and V transposed [d][j] (both pad-72)
        {
            int j = tid >> 2, s1 = tid & 3;
            const unsigned short* ksrc = qkv + (size_t)(kb + j) * D3 + 768 + h * 64;
            u16x8 k0v = *(const u16x8*)(ksrc + s1 * 8);
            u16x8 k1v = *(const u16x8*)(ksrc + (s1 + 4) * 8);
            *(u16x8*)(Ks + j * 72 + s1 * 8) = k0v;
            *(u16x8*)(Ks + j * 72 + (s1 + 4) * 8) = k1v;
            const unsigned short* vsrc = qkv + (size_t)(kb + j) * D3 + 1536 + h * 64;
            u16x8 v0v = *(const u16x8*)(vsrc + s1 * 8);
            u16x8 v1v = *(const u16x8*)(vsrc + (s1 + 4) * 8);
            #pragma unroll
            for (int e = 0; e < 8; ++e) {
                Vt[(s1 * 8 + e) * 72 + j] = v0v[e];
                Vt[((s1 + 4) * 8 + e) * 72 + j] = v1v[e];
            }
        }
        __syncthreads();

        // QK^T: S[q 16][j 64] per wave
        bf16x8 aq0 = *(const bf16x8*)(Qs + (16 * w + (lane & 15)) * 72 + (lane >> 4) * 8);
        bf16x8 aq1 = *(const bf16x8*)(Qs + (16 * w + (lane & 15)) * 72 + 32 + (lane >> 4) * 8);
        f32x4 sacc[4];
        #pragma unroll
        for (int nb = 0; nb < 4; ++nb) {
            sacc[nb] = (f32x4){0, 0, 0, 0};
            bf16x8 bk0 = *(const bf16x8*)(Ks + (nb * 16 + (lane & 15)) * 72 + (lane >> 4) * 8);
            bf16x8 bk1 = *(const bf16x8*)(Ks + (nb * 16 + (lane & 15)) * 72 + 32 + (lane >> 4) * 8);
            sacc[nb] = __builtin_amdgcn_mfma_f32_16x16x32_bf16(aq0, bk0, sacc[nb], 0, 0, 0);
            sacc[nb] = __builtin_amdgcn_mfma_f32_16x16x32_bf16(aq1, bk1, sacc[nb], 0, 0, 0);
        }
        // mask + scale (C-frag: row q = (lane>>4)*4+r, col j = nb*16 + (lane&15))
        #pragma unroll
        for (int nb = 0; nb < 4; ++nb)
            #pragma unroll
            for (int r = 0; r < 4; ++r) {
                int iqr = iq + r;
                int j = kb + nb * 16 + (lane & 15);
                bool vis = (j <= iqr) && ((j < nsink) || (j > iqr - wsize));
                sacc[nb][r] = vis ? sacc[nb][r] * 0.125f : -1e30f;
            }
        // online softmax per row
        float alpha[4];
        #pragma unroll
        for (int r = 0; r < 4; ++r) {
            float mt = fmaxf(fmaxf(sacc[0][r], sacc[1][r]), fmaxf(sacc[2][r], sacc[3][r]));
            mt = fmaxf(mt, __shfl_xor(mt, 1));
            mt = fmaxf(mt, __shfl_xor(mt, 2));
            mt = fmaxf(mt, __shfl_xor(mt, 4));
            mt = fmaxf(mt, __shfl_xor(mt, 8));
            float mn = fmaxf(mrow[r], mt);
            alpha[r] = __expf(mrow[r] - mn);
            mrow[r] = mn;
            bool dead = (mn <= -1e29f);   // no visible key yet for this row
            float rs = 0.f;
            #pragma unroll
            for (int nb = 0; nb < 4; ++nb) {
                float p = dead ? 0.f : __expf(sacc[nb][r] - mn);
                sacc[nb][r] = p;
                rs += p;
            }
            rs += __shfl_xor(rs, 1); rs += __shfl_xor(rs, 2);
            rs += __shfl_xor(rs, 4); rs += __shfl_xor(rs, 8);
            lrow[r] = lrow[r] * alpha[r] + rs;
        }
        // rescale ctx, write P (per-wave region rows 16w..16w+15)
        #pragma unroll
        for (int nb = 0; nb < 4; ++nb)
            #pragma unroll
            for (int r = 0; r < 4; ++r) ctxacc[nb][r] *= alpha[r];
        #pragma unroll
        for (int r = 0; r < 4; ++r)
            #pragma unroll
            for (int nb = 0; nb < 4; ++nb)
                Ps[(16 * w + (lane >> 4) * 4 + r) * 72 + nb * 16 + (lane & 15)] = f2bf(sacc[nb][r]);
        // PV: ctx[q 16][d 64] += P[16x64] @ V[64x64]
        bf16x8 pa0 = *(const bf16x8*)(Ps + (16 * w + (lane & 15)) * 72 + (lane >> 4) * 8);
        bf16x8 pa1 = *(const bf16x8*)(Ps + (16 * w + (lane & 15)) * 72 + 32 + (lane >> 4) * 8);
        #pragma unroll
        for (int nb = 0; nb < 4; ++nb) {
            bf16x8 bv0 = *(const bf16x8*)(Vt + (nb * 16 + (lane & 15)) * 72 + (lane >> 4) * 8);
            bf16x8 bv1 = *(const bf16x8*)(Vt + (nb * 16 + (lane & 15)) * 72 + 32 + (lane >> 4) * 8);
            ctxacc[nb] = __builtin_amdgcn_mfma_f32_16x16x32_bf16(pa0, bv0, ctxacc[nb], 0, 0, 0);
            ctxacc[nb] = __builtin_amdgcn_mfma_f32_16x16x32_bf16(pa1, bv1, ctxacc[nb], 0, 0, 0);
        }
    }

    // finalize: ctx/l -> bf16
    #pragma unroll
    for (int r = 0; r < 4; ++r) {
        float inv = 1.f / lrow[r];
        int row = i0 + 16 * w + ((lane >> 4) << 2) + r;
        #pragma unroll
        for (int nb = 0; nb < 4; ++nb)
            ctx[(size_t)row * 768 + h * 64 + nb * 16 + (lane & 15)] = f2bf(ctxacc[nb][r] * inv);
    }
}

extern "C" void kernel_launch(void* const* d_in, const int* in_sizes, int n_in,
                              void* d_out, int out_size, void* d_ws, size_t ws_size,
                              hipStream_t stream) {
    const float* x      = (const float*)d_in[0];
    const float* w_attn = (const float*)d_in[1];
    const float* b_attn = (const float*)d_in[2];
    const float* w_proj = (const float*)d_in[3];
    const float* b_proj = (const float*)d_in[4];
    const int*   pnsink = (const int*)d_in[5];
    const int*   pwin   = (const int*)d_in[6];
    float* out = (float*)d_out;

    const int D = 768, S = 4096, N1 = 3 * D;

    unsigned short* xbf   = (unsigned short*)d_ws;
    unsigned short* waT   = xbf + (size_t)S * D;
    unsigned short* wpT   = waT + (size_t)N1 * D;
    unsigned short* qkvbf = wpT + (size_t)D * D;
    unsigned short* ctxbf = qkvbf + (size_t)S * N1;

    // prep: casts + weight transposes
    cast_f32_bf16<<<(S * D / 8 + 255) / 256, 256, 0, stream>>>(x, xbf, S * D / 8);
    {
        dim3 g(N1 / 64, D / 64);
        transpose_cast<<<g, 256, 0, stream>>>(w_attn, waT, D, N1);
    }
    {
        dim3 g(D / 64, D / 64);
        transpose_cast<<<g, 256, 0, stream>>>(w_proj, wpT, D, D);
    }
    // GEMM1: qkv = x @ w_attn + b_attn  -> bf16 [S, 3D]
    {
        dim3 g(N1 / 128, S / 128);
        gemm_bf16<1><<<g, 256, 0, stream>>>(xbf, waT, b_attn, qkvbf, S, N1, D);
    }
    // attention -> ctx bf16 [S, D]
    {
        dim3 g(S / 64, 12);
        attn_mfma<<<g, 256, 0, stream>>>(qkvbf, ctxbf, pnsink, pwin);
    }
    // GEMM2: out = ctx @ w_proj + b_proj -> f32
    {
        dim3 g(D / 128, S / 128);
        gemm_bf16<0><<<g, 256, 0, stream>>>(ctxbf, wpT, b_proj, out, S, D, D);
    }
}